// Round 1
// baseline (48.869 us; speedup 1.0000x reference)
//
#include <hip/hip_runtime.h>

#define EPS 1e-7f

__global__ __launch_bounds__(256) void iou_partial_kernel(
    const float4* __restrict__ preds, const float4* __restrict__ gts,
    float* __restrict__ partial, int n) {
    int tid = blockIdx.x * blockDim.x + threadIdx.x;
    int stride = gridDim.x * blockDim.x;

    float acc = 0.0f;
    for (int i = tid; i < n; i += stride) {
        float4 p = preds[i];   // x, y, w, h
        float4 g = gts[i];

        float hw1 = 0.5f * p.z, hh1 = 0.5f * p.w;
        float hw2 = 0.5f * g.z, hh2 = 0.5f * g.w;

        float b1x1 = p.x - hw1, b1x2 = p.x + hw1;
        float b1y1 = p.y - hh1, b1y2 = p.y + hh1;
        float b2x1 = g.x - hw2, b2x2 = g.x + hw2;
        float b2y1 = g.y - hh2, b2y2 = g.y + hh2;

        float iw = fmaxf(fminf(b1x2, b2x2) - fmaxf(b1x1, b2x1), 0.0f);
        float ih = fmaxf(fminf(b1y2, b2y2) - fmaxf(b1y1, b2y1), 0.0f);
        float inter = iw * ih;
        float uni = p.z * p.w + g.z * g.w - inter + EPS;
        float iou = inter / uni;
        iou = (iou == 0.0f) ? EPS : iou;   // jnp.where(iou==0, iou+eps, iou)
        acc += __logf(iou);
    }

    // 64-lane wave reduction
    #pragma unroll
    for (int off = 32; off > 0; off >>= 1)
        acc += __shfl_down(acc, off, 64);

    __shared__ float s[4];
    int lane = threadIdx.x & 63;
    int wv = threadIdx.x >> 6;
    if (lane == 0) s[wv] = acc;
    __syncthreads();
    if (threadIdx.x == 0)
        partial[blockIdx.x] = s[0] + s[1] + s[2] + s[3];
}

__global__ __launch_bounds__(256) void iou_final_kernel(
    const float* __restrict__ partial, int nb, float* __restrict__ out, float inv_n) {
    double acc = 0.0;
    for (int i = threadIdx.x; i < nb; i += blockDim.x)
        acc += (double)partial[i];

    #pragma unroll
    for (int off = 32; off > 0; off >>= 1)
        acc += __shfl_down(acc, off, 64);

    __shared__ double s[4];
    int lane = threadIdx.x & 63;
    int wv = threadIdx.x >> 6;
    if (lane == 0) s[wv] = acc;
    __syncthreads();
    if (threadIdx.x == 0) {
        double total = s[0] + s[1] + s[2] + s[3];
        out[0] = (float)(-total * (double)inv_n);
    }
}

extern "C" void kernel_launch(void* const* d_in, const int* in_sizes, int n_in,
                              void* d_out, int out_size, void* d_ws, size_t ws_size,
                              hipStream_t stream) {
    const float4* preds = (const float4*)d_in[0];
    const float4* gts   = (const float4*)d_in[1];
    int n = in_sizes[0] / 4;           // number of boxes

    float* partial = (float*)d_ws;
    float* out = (float*)d_out;

    const int BLOCKS = 2048;
    const int THREADS = 256;

    iou_partial_kernel<<<BLOCKS, THREADS, 0, stream>>>(preds, gts, partial, n);
    iou_final_kernel<<<1, THREADS, 0, stream>>>(partial, BLOCKS, out, 1.0f / (float)n);
}